// Round 1
// baseline (263.070 us; speedup 1.0000x reference)
//
#include <hip/hip_runtime.h>
#include <cstdint>

#define TS 8192      // tokens (S)
#define TD 4096      // model dim (D)
#define TE 64        // experts (E)
#define TCAP 128     // capacity

static constexpr size_t SEC = (size_t)TS * TE * TCAP;  // 67,108,864

// ---------------------------------------------------------------------------
// Kernel 1: logits GEMM (x[S,D] · wg[E,D]^T) + row softmax + argmax, fused.
// 256 blocks x 256 threads; each block: 32 tokens x 64 experts.
// Writes per-token: expert index, top-gate value (=1/Z); per-block: partial
// column sums of the softmax (for l_aux's `me`).
// ---------------------------------------------------------------------------
__global__ __launch_bounds__(256) void gate_gemm_softmax(
    const float* __restrict__ x, const float* __restrict__ wg,
    int* __restrict__ eidx, float* __restrict__ gtop,
    float* __restrict__ partial_me)
{
    __shared__ float xs[64][34];   // [k][token]  (pad 34: float2 reads stay 8B-aligned)
    __shared__ float wsh[64][68];  // [k][expert] (pad 68: float4 reads stay 16B-aligned)
    __shared__ float cs[4][64];

    const int tid = threadIdx.x;
    const int tx = tid & 15;   // expert group (4 experts)
    const int ty = tid >> 4;   // token group  (2 tokens)
    const int tok0 = blockIdx.x * 32;

    float acc[2][4] = {{0.f,0.f,0.f,0.f},{0.f,0.f,0.f,0.f}};

    for (int d0 = 0; d0 < TD; d0 += 64) {
        // stage x tile (32 tokens x 64 d) transposed into LDS
        #pragma unroll
        for (int r = 0; r < 2; ++r) {
            const int t = r * 16 + ty;
            const float4 v = *reinterpret_cast<const float4*>(
                &x[(size_t)(tok0 + t) * TD + d0 + tx * 4]);
            xs[tx*4+0][t] = v.x; xs[tx*4+1][t] = v.y;
            xs[tx*4+2][t] = v.z; xs[tx*4+3][t] = v.w;
        }
        // stage wg tile (64 experts x 64 d) transposed into LDS
        #pragma unroll
        for (int r = 0; r < 4; ++r) {
            const int e = r * 16 + ty;
            const float4 v = *reinterpret_cast<const float4*>(
                &wg[(size_t)e * TD + d0 + tx * 4]);
            wsh[tx*4+0][e] = v.x; wsh[tx*4+1][e] = v.y;
            wsh[tx*4+2][e] = v.z; wsh[tx*4+3][e] = v.w;
        }
        __syncthreads();
        #pragma unroll
        for (int k = 0; k < 64; ++k) {
            const float2 a = *reinterpret_cast<const float2*>(&xs[k][ty*2]);
            const float4 b = *reinterpret_cast<const float4*>(&wsh[k][tx*4]);
            acc[0][0] = fmaf(a.x, b.x, acc[0][0]);
            acc[0][1] = fmaf(a.x, b.y, acc[0][1]);
            acc[0][2] = fmaf(a.x, b.z, acc[0][2]);
            acc[0][3] = fmaf(a.x, b.w, acc[0][3]);
            acc[1][0] = fmaf(a.y, b.x, acc[1][0]);
            acc[1][1] = fmaf(a.y, b.y, acc[1][1]);
            acc[1][2] = fmaf(a.y, b.z, acc[1][2]);
            acc[1][3] = fmaf(a.y, b.w, acc[1][3]);
        }
        __syncthreads();
    }

    // Fused softmax + argmax. Row (one token) spans 16 lanes x 4 regs.
    // Lane bits 0..3 == tx, so xor-butterfly over {1,2,4,8} reduces the row.
    float colsum[4] = {0.f, 0.f, 0.f, 0.f};
    #pragma unroll
    for (int r = 0; r < 2; ++r) {
        float lm = fmaxf(fmaxf(acc[r][0], acc[r][1]), fmaxf(acc[r][2], acc[r][3]));
        #pragma unroll
        for (int mask = 1; mask <= 8; mask <<= 1)
            lm = fmaxf(lm, __shfl_xor(lm, mask));
        float p[4]; float ls = 0.f;
        #pragma unroll
        for (int j = 0; j < 4; ++j) { p[j] = __expf(acc[r][j] - lm); ls += p[j]; }
        #pragma unroll
        for (int mask = 1; mask <= 8; mask <<= 1)
            ls += __shfl_xor(ls, mask);
        const float invZ = 1.0f / ls;   // gate of the argmax expert (exp(0)/Z)

        // argmax with lowest-index tie-break (matches jnp.argmax)
        float bv = acc[r][0]; int bi = tx * 4;
        #pragma unroll
        for (int j = 1; j < 4; ++j)
            if (acc[r][j] > bv) { bv = acc[r][j]; bi = tx * 4 + j; }
        #pragma unroll
        for (int mask = 1; mask <= 8; mask <<= 1) {
            const float ov = __shfl_xor(bv, mask);
            const int   oi = __shfl_xor(bi, mask);
            if (ov > bv || (ov == bv && oi < bi)) { bv = ov; bi = oi; }
        }
        if (tx == 0) {
            const int s = tok0 + ty * 2 + r;
            eidx[s] = bi;
            gtop[s] = invZ;
        }
        #pragma unroll
        for (int j = 0; j < 4; ++j) colsum[j] += p[j] * invZ;
    }

    // Deterministic column-sum reduction over the 16 ty groups.
    #pragma unroll
    for (int j = 0; j < 4; ++j) {
        colsum[j] += __shfl_xor(colsum[j], 16);
        colsum[j] += __shfl_xor(colsum[j], 32);
    }
    const int wave = tid >> 6;
    const int lane = tid & 63;
    if (lane < 16) {
        #pragma unroll
        for (int j = 0; j < 4; ++j) cs[wave][lane * 4 + j] = colsum[j];
    }
    __syncthreads();
    if (tid < 64) {
        partial_me[(size_t)blockIdx.x * 64 + tid] =
            cs[0][tid] + cs[1][tid] + cs[2][tid] + cs[3][tid];
    }
}

// ---------------------------------------------------------------------------
// Kernel 2: per-expert ordered rank (token-index order), capacity truncation,
// scatter of combine weight + dispatch mask, pre-capacity counts.
// 64 blocks (one per expert) x 256 threads; ballot-based ordered prefix sum.
// ---------------------------------------------------------------------------
__global__ __launch_bounds__(256) void rank_scatter(
    const int* __restrict__ eidx, const float* __restrict__ gtop,
    float* __restrict__ out, int* __restrict__ counts)
{
    const int e = blockIdx.x;
    const int tid = threadIdx.x;
    const int wave = tid >> 6;
    const int lane = tid & 63;
    __shared__ int wave_tot[4];

    int running = 0;  // per-thread copy; identical across threads
    for (int s0 = 0; s0 < TS; s0 += 256) {
        const int s = s0 + tid;
        const bool m = (eidx[s] == e);
        const unsigned long long b = __ballot(m);
        if (lane == 0) wave_tot[wave] = __popcll(b);
        __syncthreads();
        int off = running;
        #pragma unroll
        for (int w = 0; w < 4; ++w) if (w < wave) off += wave_tot[w];
        const int rank = off + __popcll(b & ((1ull << lane) - 1ull));
        if (m && rank < TCAP) {
            const size_t base = 1 + ((size_t)s * TE + e) * TCAP + (size_t)rank;
            out[base] = gtop[s];        // combine_weights
            out[base + SEC] = 1.0f;     // dispatch_mask (as float)
        }
        running += wave_tot[0] + wave_tot[1] + wave_tot[2] + wave_tot[3];
        __syncthreads();   // protect wave_tot before next chunk overwrites it
    }
    if (tid == 0) {
        counts[e] = running;                       // pre-capacity count
        out[1 + 2 * SEC + e] = (float)running;     // exp_counts output
    }
}

// ---------------------------------------------------------------------------
// Kernel 3: l_aux = sum_e (mean_s gates[s,e]) * (counts[e]/S) * E
// ---------------------------------------------------------------------------
__global__ __launch_bounds__(64) void finalize_laux(
    const float* __restrict__ partial_me, const int* __restrict__ counts,
    float* __restrict__ out)
{
    const int e = threadIdx.x;  // 64 threads
    float s = 0.f;
    for (int b = 0; b < 256; ++b) s += partial_me[(size_t)b * 64 + e];
    const float me = s * (1.0f / TS);
    const float ce = (float)counts[e] * (1.0f / TS);
    float v = me * ce;
    #pragma unroll
    for (int mask = 32; mask >= 1; mask >>= 1) v += __shfl_xor(v, mask);
    if (e == 0) out[0] = v * (float)TE;
}

extern "C" void kernel_launch(void* const* d_in, const int* in_sizes, int n_in,
                              void* d_out, int out_size, void* d_ws, size_t ws_size,
                              hipStream_t stream) {
    const float* x  = (const float*)d_in[0];
    const float* wg = (const float*)d_in[1];
    float* out = (float*)d_out;

    // workspace layout
    int*   eidx       = (int*)d_ws;                           // TS ints
    float* gtop       = (float*)((char*)d_ws + TS * 4);       // TS floats
    float* partial_me = gtop + TS;                            // 256*64 floats
    int*   counts     = (int*)(partial_me + 256 * 64);        // TE ints

    // Outputs are ~all zero (sparse scatter) — zero the whole buffer first.
    hipMemsetAsync(d_out, 0, (size_t)out_size * sizeof(float), stream);

    hipLaunchKernelGGL(gate_gemm_softmax, dim3(256), dim3(256), 0, stream,
                       x, wg, eidx, gtop, partial_me);
    hipLaunchKernelGGL(rank_scatter, dim3(64), dim3(256), 0, stream,
                       eidx, gtop, out, counts);
    hipLaunchKernelGGL(finalize_laux, dim3(1), dim3(64), 0, stream,
                       partial_me, counts, out);
}